// Round 15
// baseline (300.254 us; speedup 1.0000x reference)
//
#include <hip/hip_runtime.h>
#include <stdint.h>

typedef unsigned short u16;
typedef __attribute__((ext_vector_type(8))) short short8;
typedef __attribute__((ext_vector_type(4))) float f32x4;
typedef __attribute__((ext_vector_type(2))) float f32x2;

#define NEG_F (-3.402823466e+38f)

__device__ __forceinline__ u16 f2bf(float x) {
    uint32_t u = __builtin_bit_cast(uint32_t, x);
    u = (u + 0x7fffu + ((u >> 16) & 1u)) >> 16;
    return (u16)u;
}

__device__ __forceinline__ void gload_lds16(const void* g, void* l) {
    __builtin_amdgcn_global_load_lds((const __attribute__((address_space(1))) void*)g,
                                     (__attribute__((address_space(3))) void*)l, 16, 0, 0);
}

__device__ __forceinline__ f32x2 pkmin2(f32x2 a, f32x2 b) {
    return f32x2{fminf(a[0], b[0]), fminf(a[1], b[1])};
}
__device__ __forceinline__ f32x2 pkmax2(f32x2 a, f32x2 b) {
    return f32x2{fmaxf(a[0], b[0]), fmaxf(a[1], b[1])};
}

// One DPP argmax step: pull (v,idx) from another lane per CTRL, keep the
// larger v (ties -> smaller idx).
template <int CTRL, int RMASK>
__device__ __forceinline__ void argmax_dpp_step(float& v, int& i) {
    const int vb = __builtin_bit_cast(int, v);
    const int vv = __builtin_amdgcn_update_dpp(vb, vb, CTRL, RMASK, 0xf, false);
    const int ii = __builtin_amdgcn_update_dpp(i, i, CTRL, RMASK, 0xf, false);
    const float fv = __builtin_bit_cast(float, vv);
    if (fv > v || (fv == v && ii < i)) { v = fv; i = ii; }
}

// Full wave64 argmax -> result lands in lane 63.
__device__ __forceinline__ void argmax_wave(float& v, int& i) {
    argmax_dpp_step<0x111, 0xf>(v, i);  // row_shr:1
    argmax_dpp_step<0x112, 0xf>(v, i);  // row_shr:2
    argmax_dpp_step<0x114, 0xf>(v, i);  // row_shr:4
    argmax_dpp_step<0x118, 0xf>(v, i);  // row_shr:8
    argmax_dpp_step<0x142, 0xa>(v, i);  // row_bcast:15 -> rows 1,3
    argmax_dpp_step<0x143, 0xc>(v, i);  // row_bcast:31 -> rows 2,3
}

// DPP u64-max / u64-min steps (register-only).
template <int CTRL, int RMASK>
__device__ __forceinline__ unsigned long long dppmax_u64(unsigned long long k) {
    const int lo = (int)(uint32_t)(k & 0xffffffffull);
    const int hi = (int)(uint32_t)(k >> 32);
    const int lo2 = __builtin_amdgcn_update_dpp(lo, lo, CTRL, RMASK, 0xf, false);
    const int hi2 = __builtin_amdgcn_update_dpp(hi, hi, CTRL, RMASK, 0xf, false);
    const unsigned long long o =
        ((unsigned long long)(uint32_t)hi2 << 32) | (uint32_t)lo2;
    return (o > k) ? o : k;
}
template <int CTRL, int RMASK>
__device__ __forceinline__ unsigned long long dppmin_u64(unsigned long long k) {
    const int lo = (int)(uint32_t)(k & 0xffffffffull);
    const int hi = (int)(uint32_t)(k >> 32);
    const int lo2 = __builtin_amdgcn_update_dpp(lo, lo, CTRL, RMASK, 0xf, false);
    const int hi2 = __builtin_amdgcn_update_dpp(hi, hi, CTRL, RMASK, 0xf, false);
    const unsigned long long o =
        ((unsigned long long)(uint32_t)hi2 << 32) | (uint32_t)lo2;
    return (o < k) ? o : k;
}

// weight transpose helper: (K,N) f32 -> (N,KP) bf16, zero-padded in K
template <int K, int N, int KP>
__device__ __forceinline__ void tp_one(const float* __restrict__ W, u16* __restrict__ Wt, int local) {
    const int n = local / KP;
    const int k = local - n * KP;
    const float v = (k < K) ? W[(size_t)k * N + n] : 0.0f;
    Wt[local] = f2bf(v);
}

// ---------------------------------------------------------------------------
// FPS v12 + fused weight transpose.
//
// Round-14 post-mortem: at 8 waves the packed-math issue cut (-16%) was
// FLAT -> the serial tail (argmax DPP chain + barrier + combine + broadcast)
// + 2-waves/SIMD issue sharing set the iteration. v12 = 4 waves (256 thr),
// 32 pts/thread (16 packed pairs), 1 wave/SIMD:
//  - per-SIMD issue 488 -> ~390 cy/iter; combine 8->4 slots (2 DPP steps);
//    4-wave barrier skew.
//  - ~190 state VGPRs under the 512-reg budget of launch_bounds(256,1);
//    asm "+v" pin prevents remat (round-4's confound, proven rounds 5-12).
//  - j-loop has ZERO memory ops -> no latency-hiding needed at 1 wave/SIMD.
// Mean uses round-4's PROVEN 256-thread virtual-thread order (q=jj&3 scalar
// accumulators ascending jj; redv[wid+4q]; ascending-w sum). d2 rounding is
// v11's exact (dx^2+dz^2)+(dy^2+dw^2). Tie rules unchanged.
// Blocks 8.. do weight transposes (all boundaries 256-aligned).
// ---------------------------------------------------------------------------
__global__ __launch_bounds__(256, 1) void fps_kernel(const float* __restrict__ coords,
                                                     const float* __restrict__ times,
                                                     float* __restrict__ cent_out,
                                                     float* __restrict__ mask_out,
                                                     const float* __restrict__ W0,
                                                     const float* __restrict__ W1,
                                                     const float* __restrict__ W2,
                                                     const float* __restrict__ W3,
                                                     const float* __restrict__ Wn0,
                                                     const float* __restrict__ Wn1,
                                                     u16* __restrict__ W0t, u16* __restrict__ W1t,
                                                     u16* __restrict__ W2t, u16* __restrict__ W3t,
                                                     u16* __restrict__ Wn0t, u16* __restrict__ Wn1t) {
    const int tid = threadIdx.x;   // 0..255

    if (blockIdx.x >= 8) {
        // ---- weight-transpose blocks ----
        const int idx = (blockIdx.x - 8) * 256 + tid;
        if (idx < 8192) tp_one<32, 256, 32>(W0, W0t, idx);
        else if (idx < 139264) tp_one<256, 512, 256>(W1, W1t, idx - 8192);
        else if (idx < 532480) tp_one<512, 768, 512>(W2, W2t, idx - 139264);
        else if (idx < 1122304) tp_one<768, 768, 768>(W3, W3t, idx - 532480);
        else if (idx < 1712128) tp_one<768, 768, 768>(Wn0, Wn0t, idx - 1122304);
        else tp_one<768, 768, 768>(Wn1, Wn1t, idx - 1712128);
        return;
    }

    // ---- FPS blocks ----
    const int b = blockIdx.x;
    const int lane = tid & 63;
    const int wid = tid >> 6;      // physical wave 0..3

    __shared__ f32x4 pts[8192];            // 128 KiB (broadcast centroid fetch)
    __shared__ f32x4 cent_lds[128];
    __shared__ unsigned long long kslot[2][4];
    __shared__ float redv[16][4];

    // two points per vector: element 0 = jj=2p, element 1 = jj=2p+1;
    // point jj lives at p = jj*256 + tid
    f32x2 X[16], Y[16], Z[16], W_[16], md2[16];
    // round-4 mean order: accumulator q = jj&3, accumulated ascending jj
    float sx[4] = {0.f, 0.f, 0.f, 0.f};
    float sy[4] = {0.f, 0.f, 0.f, 0.f};
    float sz[4] = {0.f, 0.f, 0.f, 0.f};
    float sw[4] = {0.f, 0.f, 0.f, 0.f};
#pragma unroll
    for (int p = 0; p < 16; ++p) {
        const int pa = (2 * p) * 256 + tid;
        const int pb = (2 * p + 1) * 256 + tid;
        const int na = b * 8192 + pa;
        const int nb = b * 8192 + pb;
        const float xa = coords[3 * na + 0], ya = coords[3 * na + 1], za = coords[3 * na + 2], wa = times[na];
        const float xb = coords[3 * nb + 0], yb = coords[3 * nb + 1], zb = coords[3 * nb + 2], wb = times[nb];
        pts[pa] = f32x4{xa, ya, za, wa};
        pts[pb] = f32x4{xb, yb, zb, wb};
        X[p] = f32x2{xa, xb};
        Y[p] = f32x2{ya, yb};
        Z[p] = f32x2{za, zb};
        W_[p] = f32x2{wa, wb};
        const int qa = (2 * p) & 3;
        const int qb = (2 * p + 1) & 3;
        sx[qa] += xa; sy[qa] += ya; sz[qa] += za; sw[qa] += wa;
        sx[qb] += xb; sy[qb] += yb; sz[qb] += zb; sw[qb] += wb;
        md2[p] = f32x2{__builtin_inff(), __builtin_inff()};
    }
#pragma unroll
    for (int p = 0; p < 16; ++p) {
        asm volatile("" : "+v"(X[p]), "+v"(Y[p]), "+v"(Z[p]), "+v"(W_[p]));
    }

#pragma unroll
    for (int q = 0; q < 4; ++q) {
        float ax = sx[q], ay = sy[q], az = sz[q], aw = sw[q];
#pragma unroll
        for (int off = 32; off > 0; off >>= 1) {
            ax += __shfl_down(ax, off);
            ay += __shfl_down(ay, off);
            az += __shfl_down(az, off);
            aw += __shfl_down(aw, off);
        }
        if (lane == 0) {
            redv[wid + 4 * q][0] = ax;
            redv[wid + 4 * q][1] = ay;
            redv[wid + 4 * q][2] = az;
            redv[wid + 4 * q][3] = aw;
        }
    }
    __syncthreads();
    float c0 = 0.f, c1 = 0.f, c2 = 0.f, c3 = 0.f;
#pragma unroll
    for (int w = 0; w < 16; ++w) { c0 += redv[w][0]; c1 += redv[w][1]; c2 += redv[w][2]; c3 += redv[w][3]; }
    c0 *= (1.0f / 8192.0f);
    c1 *= (1.0f / 8192.0f);
    c2 *= (1.0f / 8192.0f);
    c3 *= (1.0f / 8192.0f);
    f32x2 cX = f32x2{c0, c0}, cY = f32x2{c1, c1}, cZ = f32x2{c2, c2}, cW = f32x2{c3, c3};

    // ---- t = 0 (peeled): distances to the mean, md untouched ----
    {
        f32x2 vp = f32x2{-__builtin_inff(), -__builtin_inff()};
        f32x2 t2[16];
#pragma unroll
        for (int p = 0; p < 16; ++p) {
            const f32x2 dX = X[p] - cX;
            const f32x2 dY = Y[p] - cY;
            const f32x2 dZ = Z[p] - cZ;
            const f32x2 dW = W_[p] - cW;
            f32x2 sA = dX * dX;
            sA += dZ * dZ;
            f32x2 sB = dY * dY;
            sB += dW * dW;
            const f32x2 d2p = sA + sB;  // v11 rounding order
            t2[p] = d2p;
            vp = pkmax2(vp, d2p);
        }
        float v = fmaxf(vp[0], vp[1]);
        int jb = 0;
#pragma unroll
        for (int p = 15; p >= 0; --p) {
            if (t2[p][1] == v) jb = 2 * p + 1;
            if (t2[p][0] == v) jb = 2 * p;
        }
        int idx = jb * 256 + tid;
        argmax_wave(v, idx);
        if (lane == 63) {
            const uint32_t bv = __builtin_bit_cast(uint32_t, v);
            const uint32_t mk = (bv & 0x80000000u) ? ~bv : (bv | 0x80000000u);
            kslot[0][wid] = ((unsigned long long)mk << 32) | (uint32_t)(0x7FFFFFFF - idx);
        }
        __syncthreads();
        unsigned long long k = kslot[0][lane & 3];
        k = dppmax_u64<0x111, 0xf>(k);
        k = dppmax_u64<0x112, 0xf>(k);   // lane3 of each row = max of 4
        const int klo = __builtin_amdgcn_readlane((int)(uint32_t)(k & 0xffffffffull), 3);
        const int sel = 0x7FFFFFFF - klo;
        const f32x4 C = pts[sel];
        cX = f32x2{C[0], C[0]}; cY = f32x2{C[1], C[1]};
        cZ = f32x2{C[2], C[2]}; cW = f32x2{C[3], C[3]};
        if (tid == (sel & 255)) {
            const int js = sel >> 8;
#pragma unroll
            for (int p = 0; p < 16; ++p) {
                if (2 * p == js) md2[p][0] = NEG_F;
                if (2 * p + 1 == js) md2[p][1] = NEG_F;
            }
        }
        if (tid == 0) cent_lds[0] = C;
    }

    // ---- t = 1..127 ----
    for (int t = 1; t < 128; ++t) {
        f32x2 vp = f32x2{-__builtin_inff(), -__builtin_inff()};
#pragma unroll
        for (int p = 0; p < 16; ++p) {
            const f32x2 dX = X[p] - cX;
            const f32x2 dY = Y[p] - cY;
            const f32x2 dZ = Z[p] - cZ;
            const f32x2 dW = W_[p] - cW;
            f32x2 sA = dX * dX;
            sA += dZ * dZ;
            f32x2 sB = dY * dY;
            sB += dW * dW;
            const f32x2 d2p = sA + sB;
            const f32x2 nmp = pkmin2(md2[p], d2p);
            md2[p] = nmp;
            vp = pkmax2(vp, nmp);
        }
        float v = fmaxf(vp[0], vp[1]);
        int jb = 0;
#pragma unroll
        for (int p = 15; p >= 0; --p) {
            if (md2[p][1] == v) jb = 2 * p + 1;
            if (md2[p][0] == v) jb = 2 * p;
        }
        int idx = jb * 256 + tid;
        argmax_wave(v, idx);
        if (lane == 63) {
            const uint32_t bv = __builtin_bit_cast(uint32_t, v);
            const uint32_t mk = (bv & 0x80000000u) ? ~bv : (bv | 0x80000000u);
            kslot[t & 1][wid] = ((unsigned long long)mk << 32) | (uint32_t)(0x7FFFFFFF - idx);
        }
        __syncthreads();
        unsigned long long k = kslot[t & 1][lane & 3];
        k = dppmax_u64<0x111, 0xf>(k);
        k = dppmax_u64<0x112, 0xf>(k);
        const int klo = __builtin_amdgcn_readlane((int)(uint32_t)(k & 0xffffffffull), 3);
        const int sel = 0x7FFFFFFF - klo;
        const f32x4 C = pts[sel];   // same address across all lanes: broadcast
        cX = f32x2{C[0], C[0]}; cY = f32x2{C[1], C[1]};
        cZ = f32x2{C[2], C[2]}; cW = f32x2{C[3], C[3]};
        if (tid == (sel & 255)) {
            const int js = sel >> 8;
#pragma unroll
            for (int p = 0; p < 16; ++p) {
                if (2 * p == js) md2[p][0] = NEG_F;
                if (2 * p + 1 == js) md2[p][1] = NEG_F;
            }
        }
        if (tid == t) cent_lds[t] = C;
    }
    // single global write after the loop
    if (tid < 128) {
        const f32x4 C = cent_lds[tid];
        f32x4* dst = (f32x4*)(cent_out + (size_t)(b * 128 + tid) * 4);
        *dst = C;
        mask_out[b * 128 + tid] = 1.0f;
    }
}

// ---------------------------------------------------------------------------
// KNN v4 (+fused gather +fused L1): unchanged from the passing round-14
// kernel.
// ---------------------------------------------------------------------------
__global__ __launch_bounds__(256) void knn_l1_kernel(const float* __restrict__ coords,
                                                     const float* __restrict__ times,
                                                     const float* __restrict__ cent,
                                                     const float* __restrict__ feat,
                                                     const u16* __restrict__ W0t,
                                                     const float* __restrict__ b0,
                                                     u16* __restrict__ h1) {
    __shared__ unsigned long long kslot[2][4];
    __shared__ int sel_lds[16];
    __shared__ __align__(16) u16 At[16 * 32];    // 1KB gathered rows
    __shared__ __align__(16) u16 Wt[256 * 32];   // 16KB W0t
    const int q = blockIdx.x;
    const int b = q >> 7;
    const int tid = threadIdx.x;
    const int lane = tid & 63;
    const int wid = tid >> 6;

    // stage W0t (8192 u16 = 1024 short8 chunks, 4 per thread)
#pragma unroll
    for (int i = 0; i < 4; ++i) {
        const int e = i * 256 + tid;            // 0..1023
        ((short8*)Wt)[e] = ((const short8*)W0t)[e];
    }

    const float c0 = cent[q * 4 + 0], c1 = cent[q * 4 + 1], c2 = cent[q * 4 + 2], c3 = cent[q * 4 + 3];
    const float cc = c0 * c0 + c1 * c1 + c2 * c2 + c3 * c3;
    float d2r[32];
#pragma unroll
    for (int s = 0; s < 32; ++s) {
        const int n = b * 8192 + s * 256 + tid;
        const float x0 = coords[3 * n], x1 = coords[3 * n + 1], x2 = coords[3 * n + 2], x3 = times[n];
        const float pp = x0 * x0 + x1 * x1 + x2 * x2 + x3 * x3;
        const float dt = x0 * c0 + x1 * c1 + x2 * c2 + x3 * c3;
        d2r[s] = cc + pp - 2.0f * dt;
    }
    for (int r = 0; r < 16; ++r) {
        float v = __builtin_inff();
        int idx = 1 << 30;
#pragma unroll
        for (int s = 0; s < 32; ++s) {
            if (d2r[s] < v) { v = d2r[s]; idx = s * 256 + tid; }
        }
        const uint32_t bv = __builtin_bit_cast(uint32_t, v);
        const uint32_t mk = (bv & 0x80000000u) ? ~bv : (bv | 0x80000000u);  // ascending map
        unsigned long long key = ((unsigned long long)mk << 32) | (uint32_t)idx;
        key = dppmin_u64<0x111, 0xf>(key);
        key = dppmin_u64<0x112, 0xf>(key);
        key = dppmin_u64<0x114, 0xf>(key);
        key = dppmin_u64<0x118, 0xf>(key);
        key = dppmin_u64<0x142, 0xa>(key);  // row_bcast:15 -> rows 1,3
        key = dppmin_u64<0x143, 0xc>(key);  // row_bcast:31 -> rows 2,3 (lane63 = wave min)
        if (lane == 63) kslot[r & 1][wid] = key;
        __syncthreads();
        unsigned long long k = kslot[r & 1][lane & 3];
        k = dppmin_u64<0x111, 0xf>(k);
        k = dppmin_u64<0x112, 0xf>(k);      // lane3 of each row = min of 4
        const int sel = __builtin_amdgcn_readlane((int)(uint32_t)(k & 0xffffffffull), 3);
        if (tid == 0) sel_lds[r] = sel;
        if (tid == (sel & 255)) {
            const int js = sel >> 8;
#pragma unroll
            for (int s = 0; s < 32; ++s)
                if (s == js) d2r[s] = __builtin_inff();
        }
    }
    __syncthreads();
    // gather 16 rows x 32 feats into At (bf16)
#pragma unroll
    for (int i = 0; i < 2; ++i) {
        const int e = i * 256 + tid;        // 0..511
        const int r = e >> 5;
        const int c = e & 31;
        const int n = b * 8192 + sel_lds[r];
        At[e] = f2bf(feat[(size_t)n * 32 + c]);
    }
    __syncthreads();
    // L1: h1(16x256) = relu(At(16x32) @ W0 + b0); 4 n-tiles per wave
    const int arow = lane & 15;
    const int koff = (lane >> 4) * 8;
    const short8 afrag = *(const short8*)(At + arow * 32 + koff);
#pragma unroll
    for (int i = 0; i < 4; ++i) {
        const int nbase = (wid * 4 + i) * 16;
        const short8 bfrag = *(const short8*)(Wt + (nbase + (lane & 15)) * 32 + koff);
        f32x4 acc = f32x4{0.f, 0.f, 0.f, 0.f};
        acc = __builtin_amdgcn_mfma_f32_16x16x32_bf16(afrag, bfrag, acc, 0, 0, 0);
        const int col = nbase + (lane & 15);
        const float bv = b0[col];
        const int row0 = (lane >> 4) * 4;
#pragma unroll
        for (int rg = 0; rg < 4; ++rg) {
            const float vv = fmaxf(acc[rg] + bv, 0.0f);
            h1[(size_t)(q * 16 + row0 + rg) * 256 + col] = f2bf(vv);
        }
    }
}

// ---------------------------------------------------------------------------
// bf16 MFMA GEMM: C(M,N) = relu?(A(M,K) @ W(K,N) + bias), W given as Wt(N,K).
// BM x 128 tile (BM = 128 or 64), BK=64, 4 waves, global_load_lds width 16,
// source-side XOR swizzle so ds_read_b128 is ~conflict-free.
// POOL=1 (BM=128 only): fuse the 16-row max-pool into the epilogue.
// ---------------------------------------------------------------------------
template <int BM, int RELU, int OUTF32, int POOL>
__global__ __launch_bounds__(256) void gemm_kernel(const u16* __restrict__ A,
                                                   const u16* __restrict__ Bt,
                                                   const float* __restrict__ bias,
                                                   void* __restrict__ Cv,
                                                   int M, int N, int K) {
    (void)M;
    constexpr int NREP = (BM == 128) ? 4 : 2;
    __shared__ __align__(16) u16 As[BM * 64];
    __shared__ __align__(16) u16 Bs[128 * 64];
    const int tid = threadIdx.x;
    const int lane = tid & 63;
    const int wid = tid >> 6;
    const int brow = blockIdx.x * BM;
    const int bcol = blockIdx.y * 128;
    const int wm = (BM == 128) ? (wid >> 1) * 64 : 0;
    const int wn = (BM == 128) ? (wid & 1) * 64 : wid * 32;

    f32x4 acc[4][NREP];
#pragma unroll
    for (int m = 0; m < 4; ++m)
#pragma unroll
        for (int n = 0; n < NREP; ++n)
            acc[m][n] = f32x4{0.f, 0.f, 0.f, 0.f};

    const int srow = tid >> 3;    // 0..31
    const int schunk = tid & 7;   // 16B chunk within a 128B row
    const uint32_t lds_wave_base = (uint32_t)(wid * 1024);

    for (int k0 = 0; k0 < K; k0 += 64) {
#pragma unroll
        for (int i = 0; i < BM / 32; ++i) {
            const int row = i * 32 + srow;
            const int sc = schunk ^ (row & 7);  // inverse-swizzled SOURCE chunk
            const u16* ga = A + (size_t)(brow + row) * K + (size_t)(k0 + sc * 8);
            const uint32_t lb = (uint32_t)(i * 4096) + lds_wave_base;
            gload_lds16(ga, (char*)As + lb);
        }
#pragma unroll
        for (int i = 0; i < 4; ++i) {
            const int row = i * 32 + srow;
            const int sc = schunk ^ (row & 7);
            const u16* gb = Bt + (size_t)(bcol + row) * K + (size_t)(k0 + sc * 8);
            const uint32_t lb = (uint32_t)(i * 4096) + lds_wave_base;
            gload_lds16(gb, (char*)Bs + lb);
        }
        __syncthreads();
#pragma unroll
        for (int kc = 0; kc < 2; ++kc) {
            short8 af[4], bfr[NREP];
#pragma unroll
            for (int m = 0; m < 4; ++m) {
                const int row = wm + m * 16 + (lane & 15);
                const int sc = (kc * 4 + (lane >> 4)) ^ (row & 7);
                af[m] = *(const short8*)(As + row * 64 + sc * 8);
            }
#pragma unroll
            for (int n = 0; n < NREP; ++n) {
                const int row = wn + n * 16 + (lane & 15);
                const int sc = (kc * 4 + (lane >> 4)) ^ (row & 7);
                bfr[n] = *(const short8*)(Bs + row * 64 + sc * 8);
            }
#pragma unroll
            for (int m = 0; m < 4; ++m)
#pragma unroll
                for (int n = 0; n < NREP; ++n)
                    acc[m][n] = __builtin_amdgcn_mfma_f32_16x16x32_bf16(af[m], bfr[n], acc[m][n], 0, 0, 0);
        }
        __syncthreads();
    }

    if (POOL) {
#pragma unroll
        for (int m = 0; m < 4; ++m) {
            const int prow = (brow >> 4) + (wm >> 4) + m;
#pragma unroll
            for (int n = 0; n < NREP; ++n) {
                float v = fmaxf(fmaxf(acc[m][n][0], acc[m][n][1]),
                                fmaxf(acc[m][n][2], acc[m][n][3]));
                v = fmaxf(v, __shfl_xor(v, 16));
                v = fmaxf(v, __shfl_xor(v, 32));
                const int col = bcol + wn + n * 16 + (lane & 15);
                v += bias[col];
                if (lane < 16) ((u16*)Cv)[(size_t)prow * N + col] = f2bf(v);
            }
        }
    } else {
#pragma unroll
        for (int m = 0; m < 4; ++m) {
            const int row0 = brow + wm + m * 16 + ((lane >> 4) << 2);
#pragma unroll
            for (int n = 0; n < NREP; ++n) {
                const int col = bcol + wn + n * 16 + (lane & 15);
                const float bv = bias[col];
#pragma unroll
                for (int r = 0; r < 4; ++r) {
                    float v = acc[m][n][r] + bv;
                    if (RELU) v = fmaxf(v, 0.0f);
                    if (OUTF32) ((float*)Cv)[(size_t)(row0 + r) * N + col] = v;
                    else ((u16*)Cv)[(size_t)(row0 + r) * N + col] = f2bf(v);
                }
            }
        }
    }
}

// ---------------------------------------------------------------------------
extern "C" void kernel_launch(void* const* d_in, const int* in_sizes, int n_in,
                              void* d_out, int out_size, void* d_ws, size_t ws_size,
                              hipStream_t stream) {
    (void)in_sizes; (void)n_in; (void)out_size; (void)ws_size;
    const float* coords = (const float*)d_in[0];
    const float* features = (const float*)d_in[1];
    const float* times = (const float*)d_in[3];
    const float* W0 = (const float*)d_in[4];
    const float* b0 = (const float*)d_in[5];
    const float* W1 = (const float*)d_in[6];
    const float* b1 = (const float*)d_in[7];
    const float* W2 = (const float*)d_in[8];
    const float* b2 = (const float*)d_in[9];
    const float* W3 = (const float*)d_in[10];
    const float* b3 = (const float*)d_in[11];
    const float* Wn0 = (const float*)d_in[12];
    const float* bn0 = (const float*)d_in[13];
    const float* Wn1 = (const float*)d_in[14];
    const float* bn1 = (const float*)d_in[15];

    char* ws = (char*)d_ws;
    u16* W0t = (u16*)(ws + 81920);            // 256x32
    u16* W1t = (u16*)(ws + 114688);           // 512x256
    u16* W2t = (u16*)(ws + 376832);           // 768x512
    u16* W3t = (u16*)(ws + 1163264);          // 768x768
    u16* Wn0t = (u16*)(ws + 2342912);         // 768x768
    u16* Wn1t = (u16*)(ws + 3522560);         // 768x768
    u16* bufX = (u16*)(ws + 4702208);         // 16384x768 bf16 max
    u16* bufY = (u16*)(ws + 29868032);        // 16384x768 bf16 max

    float* tokens_out = (float*)d_out;                    // (8,128,768)
    float* cent_out = (float*)d_out + 786432;             // (8,128,4)
    float* mask_out = (float*)d_out + 786432 + 4096;      // (8,128)

    // FPS (blocks 0-7) + all weight transposes (blocks 8..8999) in one launch
    fps_kernel<<<9000, 256, 0, stream>>>(coords, times, cent_out, mask_out,
                                         W0, W1, W2, W3, Wn0, Wn1,
                                         W0t, W1t, W2t, W3t, Wn0t, Wn1t);
    // KNN top-16 + fused gather + fused L1 -> h1 (16384x256 bf16) in bufX
    knn_l1_kernel<<<1024, 256, 0, stream>>>(coords, times, cent_out, features,
                                            W0t, b0, bufX);

    // MLP layers 2-4 on gathered rows (M = 16384)
    gemm_kernel<128, 1, 0, 0><<<dim3(128, 4), 256, 0, stream>>>(bufX, W1t, b1, bufY, 16384, 512, 256);
    gemm_kernel<128, 1, 0, 0><<<dim3(128, 6), 256, 0, stream>>>(bufY, W2t, b2, bufX, 16384, 768, 512);
    // layer 4 with fused 16-row max-pool -> pooled (1024x768) in bufY
    gemm_kernel<128, 0, 0, 1><<<dim3(128, 6), 256, 0, stream>>>(bufX, W3t, b3, bufY, 16384, 768, 768);

    // token MLP (M = 1024) -- BM=64 tiles double the grid to 96 blocks
    gemm_kernel<64, 1, 0, 0><<<dim3(16, 6), 256, 0, stream>>>(bufY, Wn0t, bn0, bufX, 1024, 768, 768);
    gemm_kernel<64, 0, 1, 0><<<dim3(16, 6), 256, 0, stream>>>(bufX, Wn1t, bn1, tokens_out, 1024, 768, 768);
}

// Round 16
// 284.164 us; speedup vs baseline: 1.0566x; 1.0566x over previous
//
#include <hip/hip_runtime.h>
#include <stdint.h>

typedef unsigned short u16;
typedef __attribute__((ext_vector_type(8))) short short8;
typedef __attribute__((ext_vector_type(4))) float f32x4;
typedef __attribute__((ext_vector_type(2))) float f32x2;

#define NEG_F (-3.402823466e+38f)

__device__ __forceinline__ u16 f2bf(float x) {
    uint32_t u = __builtin_bit_cast(uint32_t, x);
    u = (u + 0x7fffu + ((u >> 16) & 1u)) >> 16;
    return (u16)u;
}

__device__ __forceinline__ void gload_lds16(const void* g, void* l) {
    __builtin_amdgcn_global_load_lds((const __attribute__((address_space(1))) void*)g,
                                     (__attribute__((address_space(3))) void*)l, 16, 0, 0);
}

__device__ __forceinline__ f32x2 pkmin2(f32x2 a, f32x2 b) {
    return f32x2{fminf(a[0], b[0]), fminf(a[1], b[1])};
}
__device__ __forceinline__ f32x2 pkmax2(f32x2 a, f32x2 b) {
    return f32x2{fmaxf(a[0], b[0]), fmaxf(a[1], b[1])};
}

// One DPP argmax step: pull (v,idx) from another lane per CTRL, keep the
// larger v (ties -> smaller idx).
template <int CTRL, int RMASK>
__device__ __forceinline__ void argmax_dpp_step(float& v, int& i) {
    const int vb = __builtin_bit_cast(int, v);
    const int vv = __builtin_amdgcn_update_dpp(vb, vb, CTRL, RMASK, 0xf, false);
    const int ii = __builtin_amdgcn_update_dpp(i, i, CTRL, RMASK, 0xf, false);
    const float fv = __builtin_bit_cast(float, vv);
    if (fv > v || (fv == v && ii < i)) { v = fv; i = ii; }
}

// Full wave64 argmax -> result lands in lane 63.
__device__ __forceinline__ void argmax_wave(float& v, int& i) {
    argmax_dpp_step<0x111, 0xf>(v, i);  // row_shr:1
    argmax_dpp_step<0x112, 0xf>(v, i);  // row_shr:2
    argmax_dpp_step<0x114, 0xf>(v, i);  // row_shr:4
    argmax_dpp_step<0x118, 0xf>(v, i);  // row_shr:8
    argmax_dpp_step<0x142, 0xa>(v, i);  // row_bcast:15 -> rows 1,3
    argmax_dpp_step<0x143, 0xc>(v, i);  // row_bcast:31 -> rows 2,3
}

// DPP u64-max / u64-min steps (register-only).
template <int CTRL, int RMASK>
__device__ __forceinline__ unsigned long long dppmax_u64(unsigned long long k) {
    const int lo = (int)(uint32_t)(k & 0xffffffffull);
    const int hi = (int)(uint32_t)(k >> 32);
    const int lo2 = __builtin_amdgcn_update_dpp(lo, lo, CTRL, RMASK, 0xf, false);
    const int hi2 = __builtin_amdgcn_update_dpp(hi, hi, CTRL, RMASK, 0xf, false);
    const unsigned long long o =
        ((unsigned long long)(uint32_t)hi2 << 32) | (uint32_t)lo2;
    return (o > k) ? o : k;
}
template <int CTRL, int RMASK>
__device__ __forceinline__ unsigned long long dppmin_u64(unsigned long long k) {
    const int lo = (int)(uint32_t)(k & 0xffffffffull);
    const int hi = (int)(uint32_t)(k >> 32);
    const int lo2 = __builtin_amdgcn_update_dpp(lo, lo, CTRL, RMASK, 0xf, false);
    const int hi2 = __builtin_amdgcn_update_dpp(hi, hi, CTRL, RMASK, 0xf, false);
    const unsigned long long o =
        ((unsigned long long)(uint32_t)hi2 << 32) | (uint32_t)lo2;
    return (o < k) ? o : k;
}

// weight transpose helper: (K,N) f32 -> (N,KP) bf16, zero-padded in K
template <int K, int N, int KP>
__device__ __forceinline__ void tp_one(const float* __restrict__ W, u16* __restrict__ Wt, int local) {
    const int n = local / KP;
    const int k = local - n * KP;
    const float v = (k < K) ? W[(size_t)k * N + n] : 0.0f;
    Wt[local] = f2bf(v);
}

// ---------------------------------------------------------------------------
// FPS v11 + fused weight transpose. (Round-14 best configuration, reverted
// from the round-15 4-wave regression: VGPR=132 < needed ~190 -> remat again;
// 8 waves x 16 pts with 88 VGPR resident state is the design-space optimum.)
// ---------------------------------------------------------------------------
__global__ __launch_bounds__(512, 2) void fps_kernel(const float* __restrict__ coords,
                                                     const float* __restrict__ times,
                                                     float* __restrict__ cent_out,
                                                     float* __restrict__ mask_out,
                                                     const float* __restrict__ W0,
                                                     const float* __restrict__ W1,
                                                     const float* __restrict__ W2,
                                                     const float* __restrict__ W3,
                                                     const float* __restrict__ Wn0,
                                                     const float* __restrict__ Wn1,
                                                     u16* __restrict__ W0t, u16* __restrict__ W1t,
                                                     u16* __restrict__ W2t, u16* __restrict__ W3t,
                                                     u16* __restrict__ Wn0t, u16* __restrict__ Wn1t) {
    const int tid = threadIdx.x;   // 0..511

    if (blockIdx.x >= 8) {
        // ---- weight-transpose blocks ----
        const int idx = (blockIdx.x - 8) * 512 + tid;
        if (idx < 8192) tp_one<32, 256, 32>(W0, W0t, idx);
        else if (idx < 139264) tp_one<256, 512, 256>(W1, W1t, idx - 8192);
        else if (idx < 532480) tp_one<512, 768, 512>(W2, W2t, idx - 139264);
        else if (idx < 1122304) tp_one<768, 768, 768>(W3, W3t, idx - 532480);
        else if (idx < 1712128) tp_one<768, 768, 768>(Wn0, Wn0t, idx - 1122304);
        else tp_one<768, 768, 768>(Wn1, Wn1t, idx - 1712128);
        return;
    }

    // ---- FPS blocks ----
    const int b = blockIdx.x;
    const int lane = tid & 63;
    const int wid = tid >> 6;      // physical wave 0..7

    __shared__ f32x4 pts[8192];            // 128 KiB (broadcast centroid fetch)
    __shared__ f32x4 cent_lds[128];
    __shared__ unsigned long long kslot[2][8];
    __shared__ float redv[16][4];

    // two points per vector: element 0 = point jj=2p, element 1 = jj=2p+1
    f32x2 X[8], Y[8], Z[8], W_[8], md2[8];
    f32x2 sxv = f32x2{0.f, 0.f}, syv = f32x2{0.f, 0.f};
    f32x2 szv = f32x2{0.f, 0.f}, swv = f32x2{0.f, 0.f};
#pragma unroll
    for (int p = 0; p < 8; ++p) {
        const int pa = (2 * p) * 512 + tid;
        const int pb = (2 * p + 1) * 512 + tid;
        const int na = b * 8192 + pa;
        const int nb = b * 8192 + pb;
        const float xa = coords[3 * na + 0], ya = coords[3 * na + 1], za = coords[3 * na + 2], wa = times[na];
        const float xb = coords[3 * nb + 0], yb = coords[3 * nb + 1], zb = coords[3 * nb + 2], wb = times[nb];
        pts[pa] = f32x4{xa, ya, za, wa};
        pts[pb] = f32x4{xb, yb, zb, wb};
        X[p] = f32x2{xa, xb};
        Y[p] = f32x2{ya, yb};
        Z[p] = f32x2{za, zb};
        W_[p] = f32x2{wa, wb};
        sxv += X[p]; syv += Y[p]; szv += Z[p]; swv += W_[p];
        md2[p] = f32x2{__builtin_inff(), __builtin_inff()};
    }
#pragma unroll
    for (int p = 0; p < 8; ++p) {
        asm volatile("" : "+v"(X[p]), "+v"(Y[p]), "+v"(Z[p]), "+v"(W_[p]));
    }

    // mean: q=jj&1 partials; sxv[q] accumulated in ascending p == ascending
    // even/odd jj -> identical order to the passing round-12 kernel
#pragma unroll
    for (int q = 0; q < 2; ++q) {
        float ax = (q == 0) ? sxv[0] : sxv[1];
        float ay = (q == 0) ? syv[0] : syv[1];
        float az = (q == 0) ? szv[0] : szv[1];
        float aw = (q == 0) ? swv[0] : swv[1];
#pragma unroll
        for (int off = 32; off > 0; off >>= 1) {
            ax += __shfl_down(ax, off);
            ay += __shfl_down(ay, off);
            az += __shfl_down(az, off);
            aw += __shfl_down(aw, off);
        }
        if (lane == 0) {
            redv[wid + 8 * q][0] = ax;
            redv[wid + 8 * q][1] = ay;
            redv[wid + 8 * q][2] = az;
            redv[wid + 8 * q][3] = aw;
        }
    }
    __syncthreads();
    float c0 = 0.f, c1 = 0.f, c2 = 0.f, c3 = 0.f;
#pragma unroll
    for (int w = 0; w < 16; ++w) { c0 += redv[w][0]; c1 += redv[w][1]; c2 += redv[w][2]; c3 += redv[w][3]; }
    c0 *= (1.0f / 8192.0f);
    c1 *= (1.0f / 8192.0f);
    c2 *= (1.0f / 8192.0f);
    c3 *= (1.0f / 8192.0f);
    f32x2 cX = f32x2{c0, c0}, cY = f32x2{c1, c1}, cZ = f32x2{c2, c2}, cW = f32x2{c3, c3};

    // ---- t = 0 (peeled): distances to the mean, md untouched ----
    {
        f32x2 vp = f32x2{-__builtin_inff(), -__builtin_inff()};
        f32x2 t2[8];
#pragma unroll
        for (int p = 0; p < 8; ++p) {
            const f32x2 dX = X[p] - cX;
            const f32x2 dY = Y[p] - cY;
            const f32x2 dZ = Z[p] - cZ;
            const f32x2 dW = W_[p] - cW;
            f32x2 sA = dX * dX;
            sA += dZ * dZ;          // {dx^2+dz^2, ...}
            f32x2 sB = dY * dY;
            sB += dW * dW;          // {dy^2+dw^2, ...}
            const f32x2 d2p = sA + sB;  // same rounding as round-12
            t2[p] = d2p;
            vp = pkmax2(vp, d2p);
        }
        float v = fmaxf(vp[0], vp[1]);
        int jb = 0;
#pragma unroll
        for (int p = 7; p >= 0; --p) {
            if (t2[p][1] == v) jb = 2 * p + 1;
            if (t2[p][0] == v) jb = 2 * p;
        }
        int idx = jb * 512 + tid;
        argmax_wave(v, idx);
        if (lane == 63) {
            const uint32_t bv = __builtin_bit_cast(uint32_t, v);
            const uint32_t mk = (bv & 0x80000000u) ? ~bv : (bv | 0x80000000u);
            kslot[0][wid] = ((unsigned long long)mk << 32) | (uint32_t)(0x7FFFFFFF - idx);
        }
        __syncthreads();
        unsigned long long k = kslot[0][lane & 7];
        k = dppmax_u64<0x111, 0xf>(k);
        k = dppmax_u64<0x112, 0xf>(k);
        k = dppmax_u64<0x114, 0xf>(k);
        const int klo = __builtin_amdgcn_readlane((int)(uint32_t)(k & 0xffffffffull), 7);
        const int sel = 0x7FFFFFFF - klo;
        const f32x4 C = pts[sel];
        cX = f32x2{C[0], C[0]}; cY = f32x2{C[1], C[1]};
        cZ = f32x2{C[2], C[2]}; cW = f32x2{C[3], C[3]};
        if (tid == (sel & 511)) {
            const int js = sel >> 9;
#pragma unroll
            for (int p = 0; p < 8; ++p) {
                if (2 * p == js) md2[p][0] = NEG_F;
                if (2 * p + 1 == js) md2[p][1] = NEG_F;
            }
        }
        if (tid == 0) cent_lds[0] = C;
    }

    // ---- t = 1..127 ----
    for (int t = 1; t < 128; ++t) {
        f32x2 vp = f32x2{-__builtin_inff(), -__builtin_inff()};
#pragma unroll
        for (int p = 0; p < 8; ++p) {
            const f32x2 dX = X[p] - cX;
            const f32x2 dY = Y[p] - cY;
            const f32x2 dZ = Z[p] - cZ;
            const f32x2 dW = W_[p] - cW;
            f32x2 sA = dX * dX;
            sA += dZ * dZ;
            f32x2 sB = dY * dY;
            sB += dW * dW;
            const f32x2 d2p = sA + sB;
            const f32x2 nmp = pkmin2(md2[p], d2p);
            md2[p] = nmp;
            vp = pkmax2(vp, nmp);
        }
        float v = fmaxf(vp[0], vp[1]);
        int jb = 0;
#pragma unroll
        for (int p = 7; p >= 0; --p) {
            if (md2[p][1] == v) jb = 2 * p + 1;
            if (md2[p][0] == v) jb = 2 * p;
        }
        int idx = jb * 512 + tid;
        argmax_wave(v, idx);
        if (lane == 63) {
            const uint32_t bv = __builtin_bit_cast(uint32_t, v);
            const uint32_t mk = (bv & 0x80000000u) ? ~bv : (bv | 0x80000000u);
            kslot[t & 1][wid] = ((unsigned long long)mk << 32) | (uint32_t)(0x7FFFFFFF - idx);
        }
        __syncthreads();
        unsigned long long k = kslot[t & 1][lane & 7];
        k = dppmax_u64<0x111, 0xf>(k);
        k = dppmax_u64<0x112, 0xf>(k);
        k = dppmax_u64<0x114, 0xf>(k);
        const int klo = __builtin_amdgcn_readlane((int)(uint32_t)(k & 0xffffffffull), 7);
        const int sel = 0x7FFFFFFF - klo;
        const f32x4 C = pts[sel];   // same address across all lanes: broadcast
        cX = f32x2{C[0], C[0]}; cY = f32x2{C[1], C[1]};
        cZ = f32x2{C[2], C[2]}; cW = f32x2{C[3], C[3]};
        if (tid == (sel & 511)) {
            const int js = sel >> 9;
#pragma unroll
            for (int p = 0; p < 8; ++p) {
                if (2 * p == js) md2[p][0] = NEG_F;
                if (2 * p + 1 == js) md2[p][1] = NEG_F;
            }
        }
        if (tid == t) cent_lds[t] = C;
    }
    // single global write after the loop
    if (tid < 128) {
        const f32x4 C = cent_lds[tid];
        f32x4* dst = (f32x4*)(cent_out + (size_t)(b * 128 + tid) * 4);
        *dst = C;
        mask_out[b * 128 + tid] = 1.0f;
    }
}

// ---------------------------------------------------------------------------
// KNN v4 (+fused gather +fused L1): unchanged from the passing round-14
// kernel.
// ---------------------------------------------------------------------------
__global__ __launch_bounds__(256) void knn_l1_kernel(const float* __restrict__ coords,
                                                     const float* __restrict__ times,
                                                     const float* __restrict__ cent,
                                                     const float* __restrict__ feat,
                                                     const u16* __restrict__ W0t,
                                                     const float* __restrict__ b0,
                                                     u16* __restrict__ h1) {
    __shared__ unsigned long long kslot[2][4];
    __shared__ int sel_lds[16];
    __shared__ __align__(16) u16 At[16 * 32];    // 1KB gathered rows
    __shared__ __align__(16) u16 Wt[256 * 32];   // 16KB W0t
    const int q = blockIdx.x;
    const int b = q >> 7;
    const int tid = threadIdx.x;
    const int lane = tid & 63;
    const int wid = tid >> 6;

    // stage W0t (8192 u16 = 1024 short8 chunks, 4 per thread)
#pragma unroll
    for (int i = 0; i < 4; ++i) {
        const int e = i * 256 + tid;            // 0..1023
        ((short8*)Wt)[e] = ((const short8*)W0t)[e];
    }

    const float c0 = cent[q * 4 + 0], c1 = cent[q * 4 + 1], c2 = cent[q * 4 + 2], c3 = cent[q * 4 + 3];
    const float cc = c0 * c0 + c1 * c1 + c2 * c2 + c3 * c3;
    float d2r[32];
#pragma unroll
    for (int s = 0; s < 32; ++s) {
        const int n = b * 8192 + s * 256 + tid;
        const float x0 = coords[3 * n], x1 = coords[3 * n + 1], x2 = coords[3 * n + 2], x3 = times[n];
        const float pp = x0 * x0 + x1 * x1 + x2 * x2 + x3 * x3;
        const float dt = x0 * c0 + x1 * c1 + x2 * c2 + x3 * c3;
        d2r[s] = cc + pp - 2.0f * dt;
    }
    for (int r = 0; r < 16; ++r) {
        float v = __builtin_inff();
        int idx = 1 << 30;
#pragma unroll
        for (int s = 0; s < 32; ++s) {
            if (d2r[s] < v) { v = d2r[s]; idx = s * 256 + tid; }
        }
        const uint32_t bv = __builtin_bit_cast(uint32_t, v);
        const uint32_t mk = (bv & 0x80000000u) ? ~bv : (bv | 0x80000000u);  // ascending map
        unsigned long long key = ((unsigned long long)mk << 32) | (uint32_t)idx;
        key = dppmin_u64<0x111, 0xf>(key);
        key = dppmin_u64<0x112, 0xf>(key);
        key = dppmin_u64<0x114, 0xf>(key);
        key = dppmin_u64<0x118, 0xf>(key);
        key = dppmin_u64<0x142, 0xa>(key);  // row_bcast:15 -> rows 1,3
        key = dppmin_u64<0x143, 0xc>(key);  // row_bcast:31 -> rows 2,3 (lane63 = wave min)
        if (lane == 63) kslot[r & 1][wid] = key;
        __syncthreads();
        unsigned long long k = kslot[r & 1][lane & 3];
        k = dppmin_u64<0x111, 0xf>(k);
        k = dppmin_u64<0x112, 0xf>(k);      // lane3 of each row = min of 4
        const int sel = __builtin_amdgcn_readlane((int)(uint32_t)(k & 0xffffffffull), 3);
        if (tid == 0) sel_lds[r] = sel;
        if (tid == (sel & 255)) {
            const int js = sel >> 8;
#pragma unroll
            for (int s = 0; s < 32; ++s)
                if (s == js) d2r[s] = __builtin_inff();
        }
    }
    __syncthreads();
    // gather 16 rows x 32 feats into At (bf16)
#pragma unroll
    for (int i = 0; i < 2; ++i) {
        const int e = i * 256 + tid;        // 0..511
        const int r = e >> 5;
        const int c = e & 31;
        const int n = b * 8192 + sel_lds[r];
        At[e] = f2bf(feat[(size_t)n * 32 + c]);
    }
    __syncthreads();
    // L1: h1(16x256) = relu(At(16x32) @ W0 + b0); 4 n-tiles per wave
    const int arow = lane & 15;
    const int koff = (lane >> 4) * 8;
    const short8 afrag = *(const short8*)(At + arow * 32 + koff);
#pragma unroll
    for (int i = 0; i < 4; ++i) {
        const int nbase = (wid * 4 + i) * 16;
        const short8 bfrag = *(const short8*)(Wt + (nbase + (lane & 15)) * 32 + koff);
        f32x4 acc = f32x4{0.f, 0.f, 0.f, 0.f};
        acc = __builtin_amdgcn_mfma_f32_16x16x32_bf16(afrag, bfrag, acc, 0, 0, 0);
        const int col = nbase + (lane & 15);
        const float bv = b0[col];
        const int row0 = (lane >> 4) * 4;
#pragma unroll
        for (int rg = 0; rg < 4; ++rg) {
            const float vv = fmaxf(acc[rg] + bv, 0.0f);
            h1[(size_t)(q * 16 + row0 + rg) * 256 + col] = f2bf(vv);
        }
    }
}

// ---------------------------------------------------------------------------
// bf16 MFMA GEMM: C(M,N) = relu?(A(M,K) @ W(K,N) + bias), W given as Wt(N,K).
// BM x 128 tile (BM = 128 or 64), BK=64, 4 waves, global_load_lds width 16,
// source-side XOR swizzle so ds_read_b128 is ~conflict-free.
// POOL=1 (BM=128 only): fuse the 16-row max-pool into the epilogue.
// ---------------------------------------------------------------------------
template <int BM, int RELU, int OUTF32, int POOL>
__global__ __launch_bounds__(256) void gemm_kernel(const u16* __restrict__ A,
                                                   const u16* __restrict__ Bt,
                                                   const float* __restrict__ bias,
                                                   void* __restrict__ Cv,
                                                   int M, int N, int K) {
    (void)M;
    constexpr int NREP = (BM == 128) ? 4 : 2;
    __shared__ __align__(16) u16 As[BM * 64];
    __shared__ __align__(16) u16 Bs[128 * 64];
    const int tid = threadIdx.x;
    const int lane = tid & 63;
    const int wid = tid >> 6;
    const int brow = blockIdx.x * BM;
    const int bcol = blockIdx.y * 128;
    const int wm = (BM == 128) ? (wid >> 1) * 64 : 0;
    const int wn = (BM == 128) ? (wid & 1) * 64 : wid * 32;

    f32x4 acc[4][NREP];
#pragma unroll
    for (int m = 0; m < 4; ++m)
#pragma unroll
        for (int n = 0; n < NREP; ++n)
            acc[m][n] = f32x4{0.f, 0.f, 0.f, 0.f};

    const int srow = tid >> 3;    // 0..31
    const int schunk = tid & 7;   // 16B chunk within a 128B row
    const uint32_t lds_wave_base = (uint32_t)(wid * 1024);

    for (int k0 = 0; k0 < K; k0 += 64) {
#pragma unroll
        for (int i = 0; i < BM / 32; ++i) {
            const int row = i * 32 + srow;
            const int sc = schunk ^ (row & 7);  // inverse-swizzled SOURCE chunk
            const u16* ga = A + (size_t)(brow + row) * K + (size_t)(k0 + sc * 8);
            const uint32_t lb = (uint32_t)(i * 4096) + lds_wave_base;
            gload_lds16(ga, (char*)As + lb);
        }
#pragma unroll
        for (int i = 0; i < 4; ++i) {
            const int row = i * 32 + srow;
            const int sc = schunk ^ (row & 7);
            const u16* gb = Bt + (size_t)(bcol + row) * K + (size_t)(k0 + sc * 8);
            const uint32_t lb = (uint32_t)(i * 4096) + lds_wave_base;
            gload_lds16(gb, (char*)Bs + lb);
        }
        __syncthreads();
#pragma unroll
        for (int kc = 0; kc < 2; ++kc) {
            short8 af[4], bfr[NREP];
#pragma unroll
            for (int m = 0; m < 4; ++m) {
                const int row = wm + m * 16 + (lane & 15);
                const int sc = (kc * 4 + (lane >> 4)) ^ (row & 7);
                af[m] = *(const short8*)(As + row * 64 + sc * 8);
            }
#pragma unroll
            for (int n = 0; n < NREP; ++n) {
                const int row = wn + n * 16 + (lane & 15);
                const int sc = (kc * 4 + (lane >> 4)) ^ (row & 7);
                bfr[n] = *(const short8*)(Bs + row * 64 + sc * 8);
            }
#pragma unroll
            for (int m = 0; m < 4; ++m)
#pragma unroll
                for (int n = 0; n < NREP; ++n)
                    acc[m][n] = __builtin_amdgcn_mfma_f32_16x16x32_bf16(af[m], bfr[n], acc[m][n], 0, 0, 0);
        }
        __syncthreads();
    }

    if (POOL) {
#pragma unroll
        for (int m = 0; m < 4; ++m) {
            const int prow = (brow >> 4) + (wm >> 4) + m;
#pragma unroll
            for (int n = 0; n < NREP; ++n) {
                float v = fmaxf(fmaxf(acc[m][n][0], acc[m][n][1]),
                                fmaxf(acc[m][n][2], acc[m][n][3]));
                v = fmaxf(v, __shfl_xor(v, 16));
                v = fmaxf(v, __shfl_xor(v, 32));
                const int col = bcol + wn + n * 16 + (lane & 15);
                v += bias[col];
                if (lane < 16) ((u16*)Cv)[(size_t)prow * N + col] = f2bf(v);
            }
        }
    } else {
#pragma unroll
        for (int m = 0; m < 4; ++m) {
            const int row0 = brow + wm + m * 16 + ((lane >> 4) << 2);
#pragma unroll
            for (int n = 0; n < NREP; ++n) {
                const int col = bcol + wn + n * 16 + (lane & 15);
                const float bv = bias[col];
#pragma unroll
                for (int r = 0; r < 4; ++r) {
                    float v = acc[m][n][r] + bv;
                    if (RELU) v = fmaxf(v, 0.0f);
                    if (OUTF32) ((float*)Cv)[(size_t)(row0 + r) * N + col] = v;
                    else ((u16*)Cv)[(size_t)(row0 + r) * N + col] = f2bf(v);
                }
            }
        }
    }
}

// ---------------------------------------------------------------------------
extern "C" void kernel_launch(void* const* d_in, const int* in_sizes, int n_in,
                              void* d_out, int out_size, void* d_ws, size_t ws_size,
                              hipStream_t stream) {
    (void)in_sizes; (void)n_in; (void)out_size; (void)ws_size;
    const float* coords = (const float*)d_in[0];
    const float* features = (const float*)d_in[1];
    const float* times = (const float*)d_in[3];
    const float* W0 = (const float*)d_in[4];
    const float* b0 = (const float*)d_in[5];
    const float* W1 = (const float*)d_in[6];
    const float* b1 = (const float*)d_in[7];
    const float* W2 = (const float*)d_in[8];
    const float* b2 = (const float*)d_in[9];
    const float* W3 = (const float*)d_in[10];
    const float* b3 = (const float*)d_in[11];
    const float* Wn0 = (const float*)d_in[12];
    const float* bn0 = (const float*)d_in[13];
    const float* Wn1 = (const float*)d_in[14];
    const float* bn1 = (const float*)d_in[15];

    char* ws = (char*)d_ws;
    u16* W0t = (u16*)(ws + 81920);            // 256x32
    u16* W1t = (u16*)(ws + 114688);           // 512x256
    u16* W2t = (u16*)(ws + 376832);           // 768x512
    u16* W3t = (u16*)(ws + 1163264);          // 768x768
    u16* Wn0t = (u16*)(ws + 2342912);         // 768x768
    u16* Wn1t = (u16*)(ws + 3522560);         // 768x768
    u16* bufX = (u16*)(ws + 4702208);         // 16384x768 bf16 max
    u16* bufY = (u16*)(ws + 29868032);        // 16384x768 bf16 max

    float* tokens_out = (float*)d_out;                    // (8,128,768)
    float* cent_out = (float*)d_out + 786432;             // (8,128,4)
    float* mask_out = (float*)d_out + 786432 + 4096;      // (8,128)

    // FPS (blocks 0-7) + all weight transposes (blocks 8..4503) in one launch
    fps_kernel<<<4504, 512, 0, stream>>>(coords, times, cent_out, mask_out,
                                         W0, W1, W2, W3, Wn0, Wn1,
                                         W0t, W1t, W2t, W3t, Wn0t, Wn1t);
    // KNN top-16 + fused gather + fused L1 -> h1 (16384x256 bf16) in bufX
    knn_l1_kernel<<<1024, 256, 0, stream>>>(coords, times, cent_out, features,
                                            W0t, b0, bufX);

    // MLP layers 2-4 on gathered rows (M = 16384)
    gemm_kernel<128, 1, 0, 0><<<dim3(128, 4), 256, 0, stream>>>(bufX, W1t, b1, bufY, 16384, 512, 256);
    gemm_kernel<128, 1, 0, 0><<<dim3(128, 6), 256, 0, stream>>>(bufY, W2t, b2, bufX, 16384, 768, 512);
    // layer 4 with fused 16-row max-pool -> pooled (1024x768) in bufY
    gemm_kernel<128, 0, 0, 1><<<dim3(128, 6), 256, 0, stream>>>(bufX, W3t, b3, bufY, 16384, 768, 768);

    // token MLP (M = 1024) -- BM=64 tiles double the grid to 96 blocks
    gemm_kernel<64, 1, 0, 0><<<dim3(16, 6), 256, 0, stream>>>(bufY, Wn0t, bn0, bufX, 1024, 768, 768);
    gemm_kernel<64, 0, 1, 0><<<dim3(16, 6), 256, 0, stream>>>(bufX, Wn1t, bn1, tokens_out, 1024, 768, 768);
}